// Round 14
// baseline (413.196 us; speedup 1.0000x reference)
//
#include <hip/hip_runtime.h>
#include <math.h>

#define KNN 30
#define SIGMA_N 0.8f
#define THRESHV 1e-3f

// ---------------- old (fallback) path constants ----------------
#define QT 32
#define NTH 256
#define CAP 160
#define CAPS 161
#define RSEL 20

// ---------------- grid path constants ----------------
#define RG 64
#define NC (RG*RG*RG)
#define RC 16                    // coarse grid (RG/4)
#define NCC (RC*RC*RC)
#define QT2 8                    // queries per block
#define NTH2 256
#define LPQ 32                   // lanes per query (half wave)
#define CAP2 320
#define CAPS2 321
#define TGT 60.0f
#define MAXR 12

// ============================================================
// ===============  OLD BRUTE-FORCE PATH (fallback) ===========
// ============================================================

__global__ void prep_pack(const float* __restrict__ src, float4* __restrict__ dst, int M) {
    int j = blockIdx.x * 256 + threadIdx.x;
    if (j < M) {
        float x = src[3*j+0], y = src[3*j+1], z = src[3*j+2];
        dst[j] = make_float4(x, y, z, 0.5f*(x*x + y*y + z*z));
    }
}

template<bool PACKED>
__device__ __forceinline__ float4 fetch_pt(const float4* __restrict__ sp,
                                           const float* __restrict__ sv, int j) {
    if (PACKED) return sp[j];
    float x = sv[3*j+0], y = sv[3*j+1], z = sv[3*j+2];
    return make_float4(x, y, z, 0.5f*(x*x + y*y + z*z));
}

__device__ __forceinline__ void ins4(unsigned int k, unsigned int &m0, unsigned int &m1,
                                     unsigned int &m2, unsigned int &m3) {
    if (k < m3) {
        if (k < m2) {
            m3 = m2;
            if (k < m1) { m2 = m1; if (k < m0) { m1 = m0; m0 = k; } else m1 = k; }
            else m2 = k;
        } else m3 = k;
    }
}

template<bool PACKED>
__global__ __launch_bounds__(NTH)
void rimls_fused(const float* __restrict__ qpts,
                 const float* __restrict__ sverts,
                 const float* __restrict__ snorms,
                 const float4* __restrict__ spack,
                 float* __restrict__ out,
                 int N, int M)
{
    __shared__ unsigned int cand[QT * CAPS];
    __shared__ unsigned int selk[QT * KNN];
    __shared__ float4 qbuf[QT];
    __shared__ unsigned int cnt[QT];
    __shared__ unsigned int T16[QT];
    __shared__ int retryq[QT];

    const int t  = threadIdx.x;
    const int qg = t >> 4;
    const int c  = t & 15;
    const int qa = qg, qb = qg + 16;

    if (t < QT) {
        int gq = blockIdx.x * QT + t; if (gq >= N) gq = N - 1;
        float x = qpts[3*gq+0], y = qpts[3*gq+1], z = qpts[3*gq+2];
        qbuf[t] = make_float4(x, y, z, 0.5f*(x*x + y*y + z*z));
    }
    for (int i = t; i < QT * KNN; i += NTH) selk[i] = 0u;
    __syncthreads();

    const float ax = qbuf[qa].x, ay = qbuf[qa].y, az = qbuf[qa].z, aw = qbuf[qa].w;
    const float bx = qbuf[qb].x, by = qbuf[qb].y, bz = qbuf[qb].z, bw = qbuf[qb].w;

    unsigned int a0=~0u,a1=~0u,a2=~0u,a3=~0u, b0=~0u,b1=~0u,b2=~0u,b3=~0u;
    {
        const int n1 = M >> 6;
        #pragma unroll 2
        for (int i = 0; i < n1; ++i) {
            int j = (c + (i << 4)) << 2;
            float4 s = fetch_pt<PACKED>(spack, sverts, j);
            float va = fmaxf(fmaf(-ax, s.x, fmaf(-ay, s.y, fmaf(-az, s.z, s.w + aw))), 0.0f);
            float vb = fmaxf(fmaf(-bx, s.x, fmaf(-by, s.y, fmaf(-bz, s.z, s.w + bw))), 0.0f);
            unsigned int ka = (__float_as_uint(va) & 0xFFFF0000u) | (unsigned int)j;
            unsigned int kb = (__float_as_uint(vb) & 0xFFFF0000u) | (unsigned int)j;
            ins4(ka, a0, a1, a2, a3);
            ins4(kb, b0, b1, b2, b3);
        }
    }
    {
        unsigned int* mb = cand;
        mb[qa*64 + c*4 + 0] = a0; mb[qa*64 + c*4 + 1] = a1;
        mb[qa*64 + c*4 + 2] = a2; mb[qa*64 + c*4 + 3] = a3;
        mb[qb*64 + c*4 + 0] = b0; mb[qb*64 + c*4 + 1] = b1;
        mb[qb*64 + c*4 + 2] = b2; mb[qb*64 + c*4 + 3] = b3;
    }
    __syncthreads();
    if (t < QT) {
        const unsigned int* m_ = cand + t * 64;
        unsigned int kth = 0xFFFFFFFFu;
        for (int a = 0; a < 64; ++a) {
            unsigned int ka = m_[a]; int r = 0;
            for (int b = 0; b < 64; ++b) r += (m_[b] < ka) ? 1 : 0;
            if (r == RSEL - 1) kth = ka;
        }
        unsigned int tb = (kth >> 16) + 1u;
        if (tb > 0x7F00u) tb = 0x7F00u;
        T16[t] = tb; cnt[t] = 0u; retryq[t] = 1;
    }
    __syncthreads();

    const int n3 = M >> 4;
    for (int round = 0; round < 8; ++round) {
        bool aa = retryq[qa] != 0, ab = retryq[qb] != 0;
        if (aa || ab) {
            float Ta = aa ? __uint_as_float(T16[qa] << 16) : 0.0f;
            float Tb = ab ? __uint_as_float(T16[qb] << 16) : 0.0f;
            #pragma unroll 4
            for (int i = 0; i < n3; ++i) {
                int j = c + (i << 4);
                float4 s = fetch_pt<PACKED>(spack, sverts, j);
                float va = fmaxf(fmaf(-ax, s.x, fmaf(-ay, s.y, fmaf(-az, s.z, s.w + aw))), 0.0f);
                float vb = fmaxf(fmaf(-bx, s.x, fmaf(-by, s.y, fmaf(-bz, s.z, s.w + bw))), 0.0f);
                if (va < Ta) {
                    unsigned int pos = atomicAdd(&cnt[qa], 1u);
                    if (pos < (unsigned)CAP)
                        cand[qa*CAPS + pos] = (__float_as_uint(va) & 0xFFFF0000u) | (unsigned int)j;
                }
                if (vb < Tb) {
                    unsigned int pos = atomicAdd(&cnt[qb], 1u);
                    if (pos < (unsigned)CAP)
                        cand[qb*CAPS + pos] = (__float_as_uint(vb) & 0xFFFF0000u) | (unsigned int)j;
                }
            }
        }
        __syncthreads();
        int bad = 0;
        if (t < QT && retryq[t]) {
            unsigned int cc = cnt[t], tb = T16[t];
            if (cc < (unsigned)KNN) {
                if (tb < 0x7F00u) {
                    tb += (1u << 7);
                    if (tb > 0x7F00u) tb = 0x7F00u;
                    bad = 1;
                }
            } else if (cc > (unsigned)CAP && round < 4 && tb > (1u << 6)) {
                tb -= (1u << 6); bad = 1;
            }
            if (bad) { T16[t] = tb; cnt[t] = 0u; }
            else retryq[t] = 0;
        }
        if (!__syncthreads_or(bad)) break;
    }

    const int qs = t >> 3, s8 = t & 7;
    {
        unsigned int cc = cnt[qs];
        int C = (int)(cc < (unsigned)CAP ? cc : (unsigned)CAP);
        const unsigned int* cd = cand + qs * CAPS;
        for (int a = s8; a < C; a += 8) {
            unsigned int ka = cd[a]; int r = 0;
            for (int b = 0; b < C; ++b) r += (cd[b] < ka) ? 1 : 0;
            if (r < KNN) selk[qs*KNN + r] = ka;
        }
    }
    __syncthreads();

    {
        const float qx = qbuf[qs].x, qy = qbuf[qs].y, qz = qbuf[qs].z;
        float px_[4], py_[4], pz_[4], nx_[4], ny_[4], nz_[4];
        float fx_[4], phi_[4], gco_[4], r2_[4];
        float dsum = 0.0f;
        #pragma unroll
        for (int u = 0; u < 4; ++u) {
            int k = s8 + 8*u;
            bool v = (k < KNN);
            int j = v ? (int)(selk[qs*KNN + k] & 0xFFFFu) : 0;
            float4 s = fetch_pt<PACKED>(spack, sverts, j);
            float px = qx - s.x, py = qy - s.y, pz = qz - s.z;
            float r2 = px*px + py*py + pz*pz;
            float nx = snorms[3*j+0], ny = snorms[3*j+1], nz = snorms[3*j+2];
            float nrm = sqrtf(nx*nx + ny*ny + nz*nz);
            float inv = 1.0f / fmaxf(nrm, 1e-8f);
            float m = v ? 1.0f : 0.0f;
            nx *= inv * m; ny *= inv * m; nz *= inv * m;
            px_[u] = px * m; py_[u] = py * m; pz_[u] = pz * m;
            nx_[u] = nx; ny_[u] = ny; nz_[u] = nz;
            r2_[u] = r2 * m;
            fx_[u] = px_[u]*nx + py_[u]*ny + pz_[u]*nz;
            dsum += v ? sqrtf(r2) : 0.0f;
            phi_[u] = m;
        }
        dsum += __shfl_xor(dsum, 1);
        dsum += __shfl_xor(dsum, 2);
        dsum += __shfl_xor(dsum, 4);
        float h = dsum * (1.0f / (float)KNN) + 1e-8f;
        float h2 = h * h;
        float c8 = -8.0f / h2;
        #pragma unroll
        for (int u = 0; u < 4; ++u) {
            float tt = fmaxf(1.0f - r2_[u] / h2, 0.0f);
            float t2 = tt * tt;
            float valid = phi_[u];
            phi_[u] = t2 * t2 * valid;
            gco_[u] = c8 * t2 * tt * valid;
        }

        const float inv_sn2 = 1.0f / (SIGMA_N * SIGMA_N);
        float f = 0.0f, gx = 0.0f, gy = 0.0f, gz = 0.0f;
        bool done = false;
        for (int it = 0; it < 3; ++it) {
            if (done) break;
            float sw=0, swf=0, sgx=0, sgy=0, sgz=0, sfx=0, sfy=0, sfz=0, snx=0, sny=0, snz=0;
            #pragma unroll
            for (int u = 0; u < 4; ++u) {
                float alpha = 1.0f;
                if (it > 0) {
                    float dx = nx_[u]-gx, dy = ny_[u]-gy, dz = nz_[u]-gz;
                    alpha = expf(-(dx*dx + dy*dy + dz*dz) * inv_sn2);
                }
                float w = alpha * phi_[u];
                float g = alpha * gco_[u];
                float gf = g * fx_[u];
                sw  += w;          swf += w * fx_[u];
                sgx += g*px_[u];   sgy += g*py_[u];   sgz += g*pz_[u];
                sfx += gf*px_[u];  sfy += gf*py_[u];  sfz += gf*pz_[u];
                snx += w*nx_[u];   sny += w*ny_[u];   snz += w*nz_[u];
            }
            #pragma unroll
            for (int m = 1; m < 8; m <<= 1) {
                sw  += __shfl_xor(sw, m);  swf += __shfl_xor(swf, m);
                sgx += __shfl_xor(sgx, m); sgy += __shfl_xor(sgy, m); sgz += __shfl_xor(sgz, m);
                sfx += __shfl_xor(sfx, m); sfy += __shfl_xor(sfy, m); sfz += __shfl_xor(sfz, m);
                snx += __shfl_xor(snx, m); sny += __shfl_xor(sny, m); snz += __shfl_xor(snz, m);
            }
            sw += 1e-8f;
            float fn  = swf / sw;
            float gnx = (sfx + snx - fn*sgx) / sw;
            float gny = (sfy + sny - fn*sgy) / sw;
            float gnz = (sfz + snz - fn*sgz) / sw;
            float delta = fabsf(fn - f);
            f = fn; gx = gnx; gy = gny; gz = gnz;
            done = (delta < THRESHV);
        }
        if (s8 == 0) {
            int gq = blockIdx.x * QT + qs;
            if (gq < N) {
                out[gq] = f;
                out[N + 3*gq + 0] = gx;
                out[N + 3*gq + 1] = gy;
                out[N + 3*gq + 2] = gz;
            }
        }
    }
}

// ============================================================
// ===============  GRID KNN PATH  ============================
// ============================================================

__device__ __forceinline__ unsigned int enc_f(float f) {
    unsigned int b = __float_as_uint(f);
    return (b & 0x80000000u) ? ~b : (b | 0x80000000u);
}
__device__ __forceinline__ float dec_f(unsigned int u) {
    unsigned int b = (u & 0x80000000u) ? (u ^ 0x80000000u) : ~u;
    return __uint_as_float(b);
}
__device__ __forceinline__ int cell_of(float v, float mn, float ics) {
    int c = (int)floorf((v - mn) * ics);
    return c < 0 ? 0 : (c >= RG ? RG-1 : c);
}
// coarse-major fine-cell index: each coarse cell's 64 fine cells (and thus its
// points after scatter) are CONTIGUOUS
__device__ __forceinline__ int fidx(int cx, int cy, int cz) {
    int cidx = (((cz >> 2)*RC + (cy >> 2))*RC + (cx >> 2));
    return (cidx << 6) | ((cz & 3) << 4) | ((cy & 3) << 2) | (cx & 3);
}
// this query group's 32-bit ballot subword (group = half of the wave64).
// Proven primitive: identical pattern used by the box-path collect and the
// radix write pass in the verified R11/R13 kernels.
__device__ __forceinline__ unsigned int gballot(bool p, int grp) {
    unsigned long long mb = __ballot(p);
    return (unsigned int)(mb >> (grp << 5));
}

// fused bbox + grid params: single block, 1024 threads
__global__ void grid_bboxparams(const float* __restrict__ sv, float* __restrict__ gp, int M) {
    __shared__ unsigned int rmn[3][16], rmx[3][16];
    const int t = threadIdx.x;
    unsigned int mn0=0xFFFFFFFFu, mn1=0xFFFFFFFFu, mn2=0xFFFFFFFFu;
    unsigned int mx0=0u, mx1=0u, mx2=0u;
    for (int i = t; i < M; i += 1024) {
        unsigned int e0 = enc_f(sv[3*i+0]);
        unsigned int e1 = enc_f(sv[3*i+1]);
        unsigned int e2 = enc_f(sv[3*i+2]);
        mn0 = min(mn0, e0); mn1 = min(mn1, e1); mn2 = min(mn2, e2);
        mx0 = max(mx0, e0); mx1 = max(mx1, e1); mx2 = max(mx2, e2);
    }
    for (int off = 1; off < 64; off <<= 1) {
        mn0 = min(mn0, (unsigned int)__shfl_xor(mn0, off));
        mn1 = min(mn1, (unsigned int)__shfl_xor(mn1, off));
        mn2 = min(mn2, (unsigned int)__shfl_xor(mn2, off));
        mx0 = max(mx0, (unsigned int)__shfl_xor(mx0, off));
        mx1 = max(mx1, (unsigned int)__shfl_xor(mx1, off));
        mx2 = max(mx2, (unsigned int)__shfl_xor(mx2, off));
    }
    if ((t & 63) == 0) {
        int w = t >> 6;
        rmn[0][w]=mn0; rmn[1][w]=mn1; rmn[2][w]=mn2;
        rmx[0][w]=mx0; rmx[1][w]=mx1; rmx[2][w]=mx2;
    }
    __syncthreads();
    if (t == 0) {
        for (int w = 1; w < 16; ++w) {
            rmn[0][0]=min(rmn[0][0],rmn[0][w]); rmn[1][0]=min(rmn[1][0],rmn[1][w]); rmn[2][0]=min(rmn[2][0],rmn[2][w]);
            rmx[0][0]=max(rmx[0][0],rmx[0][w]); rmx[1][0]=max(rmx[1][0],rmx[1][w]); rmx[2][0]=max(rmx[2][0],rmx[2][w]);
        }
        float csmin = 1e30f, vcell = 1.0f;
        for (int a = 0; a < 3; ++a) {
            float mn = dec_f(rmn[a][0]), mx = dec_f(rmx[a][0]);
            float span = mx - mn;
            if (!(span > 1e-5f)) span = 1e-5f;
            float cs = span / (float)RG;
            gp[a] = mn; gp[3+a] = cs; gp[6+a] = 1.0f / cs;
            csmin = fminf(csmin, cs); vcell *= cs;
        }
        gp[9]  = 1.0f / csmin;
        gp[10] = vcell;
    }
}

__global__ void grid_count(const float* __restrict__ sv, const float* __restrict__ gp,
                           unsigned int* __restrict__ offs, int M) {
    int i = blockIdx.x * 256 + threadIdx.x;
    if (i >= M) return;
    int cx = cell_of(sv[3*i+0], gp[0], gp[6]);
    int cy = cell_of(sv[3*i+1], gp[1], gp[7]);
    int cz = cell_of(sv[3*i+2], gp[2], gp[8]);
    atomicAdd(&offs[fidx(cx, cy, cz)], 1u);
}

__global__ void grid_scan_tile(unsigned int* __restrict__ offs, unsigned int* __restrict__ aux) {
    __shared__ unsigned int sm[256];
    const int tid = threadIdx.x;
    const int base = blockIdx.x * 1024 + tid * 4;
    uint4 v = *(const uint4*)&offs[base];
    v.y += v.x; v.z += v.y; v.w += v.z;
    sm[tid] = v.w;
    __syncthreads();
    for (int off = 1; off < 256; off <<= 1) {
        unsigned int add = (tid >= off) ? sm[tid - off] : 0u;
        __syncthreads();
        sm[tid] += add;
        __syncthreads();
    }
    unsigned int add = tid ? sm[tid-1] : 0u;
    v.x += add; v.y += add; v.z += add; v.w += add;
    *(uint4*)&offs[base] = v;
    if (tid == 255) aux[blockIdx.x] = sm[255];
}

__global__ void grid_scan_aux(unsigned int* __restrict__ aux) {
    __shared__ unsigned int sm[256];
    const int tid = threadIdx.x;
    sm[tid] = aux[tid];
    __syncthreads();
    for (int off = 1; off < 256; off <<= 1) {
        unsigned int add = (tid >= off) ? sm[tid - off] : 0u;
        __syncthreads();
        sm[tid] += add;
        __syncthreads();
    }
    aux[tid] = tid ? sm[tid-1] : 0u;
}

__global__ void grid_scan_add(unsigned int* __restrict__ offs, const unsigned int* __restrict__ aux) {
    __shared__ unsigned int sm[1024];
    const int tid = threadIdx.x;
    const int base = blockIdx.x * 1024;
    uint4 v = *(const uint4*)&offs[base + tid*4];
    sm[tid*4+0] = v.x; sm[tid*4+1] = v.y; sm[tid*4+2] = v.z; sm[tid*4+3] = v.w;
    __syncthreads();
    unsigned int a = aux[blockIdx.x];
    uint4 o;
    o.x = a + (tid ? sm[tid*4-1] : 0u);
    o.y = a + sm[tid*4+0];
    o.z = a + sm[tid*4+1];
    o.w = a + sm[tid*4+2];
    *(uint4*)&offs[base + tid*4] = o;
}

__global__ void grid_scatter(const float* __restrict__ sv, const float* __restrict__ gp,
                             unsigned int* __restrict__ offs, float4* __restrict__ spts, int M) {
    int i = blockIdx.x * 256 + threadIdx.x;
    if (i >= M) return;
    float x = sv[3*i+0], y = sv[3*i+1], z = sv[3*i+2];
    int cx = cell_of(x, gp[0], gp[6]);
    int cy = cell_of(y, gp[1], gp[7]);
    int cz = cell_of(z, gp[2], gp[8]);
    unsigned int pos = atomicAdd(&offs[fidx(cx, cy, cz)], 1u);
    spts[pos] = make_float4(x, y, z, __uint_as_float((unsigned int)i));
}

// derive u16 coarse counts once (post-scatter cellend)
__global__ void grid_coarse16(const unsigned int* __restrict__ cellend,
                              unsigned short* __restrict__ c16) {
    int i = blockIdx.x * 256 + threadIdx.x;
    if (i >= NCC) return;
    unsigned int e_ = cellend[(i << 6) + 63];
    unsigned int b_ = i ? cellend[(i << 6) - 1] : 0u;
    unsigned int v = e_ - b_;
    c16[i] = (unsigned short)(v > 65535u ? 65535u : v);
}

// scan a contiguous point range with threshold filter; aborts on overshoot
__device__ __forceinline__ void scan_range(const float4* __restrict__ spts,
                                           unsigned int b_, unsigned int e_,
                                           float qx, float qy, float qz, float T2,
                                           unsigned int* cntp, unsigned int* candp) {
    for (unsigned int p = b_; p < e_; ++p) {
        if (((p - b_) & 15u) == 0u &&
            *(volatile unsigned int*)cntp > (unsigned)CAP2) return;
        float4 sp = spts[p];
        float ex = qx - sp.x, ey = qy - sp.y, ez = qz - sp.z;
        float d2 = fmaf(ex, ex, fmaf(ey, ey, ez*ez));
        if (d2 < T2) {
            unsigned int pos = atomicAdd(cntp, 1u);
            if (pos < (unsigned)CAP2)
                candp[pos] = (__float_as_uint(d2) & 0xFFFF0000u) | (__float_as_uint(sp.w) & 0xFFFFu);
        }
    }
}

// Exact selection of the KNN smallest among C DISTINCT keys (distinctness:
// low 16 bits are the unique point index). Writes the selected set to
// sel[0..min(C,KNN)) in ARBITRARY order (consumer is order-independent),
// returns the max selected key (the exact "30th-smallest"). 4-bit MSD radix
// with early termination. ONLY change vs the verified R13 version: histogram
// counting uses register bins + ballot/popc instead of LDS atomicAdds
// (same counts, no LDS traffic). Control flow, bound arithmetic, and the
// write pass are byte-identical to R13.
__device__ __forceinline__ unsigned int radix_select(
        const unsigned int* __restrict__ cd, int C,
        unsigned int* __restrict__ sel, int l, int grp)
{
    unsigned int kmx = 0u;
    if (C <= KNN) {
        for (int a = l; a < C; a += LPQ) {
            unsigned int k = cd[a];
            sel[a] = k;
            kmx = kmx > k ? kmx : k;
        }
    } else {
        unsigned int pref = 0u, prefmask = 0u;
        int need = KNN;
        unsigned long long bound = 0ull;
        for (int shift = 28; shift >= 0; shift -= 4) {
            int hist[16];
            #pragma unroll
            for (int b = 0; b < 16; ++b) hist[b] = 0;
            for (int a0 = 0; a0 < C; a0 += LPQ) {
                int a = a0 + l;
                unsigned int k = (a < C) ? cd[a] : 0u;
                bool match = (a < C) && ((k & prefmask) == pref);
                unsigned int bin = (k >> shift) & 15u;
                #pragma unroll
                for (int b = 0; b < 16; ++b)
                    hist[b] += __popc(gballot(match && (bin == (unsigned)b), grp));
            }
            int cum = 0, bsel = 0, cntb = 0;
            #pragma unroll 1
            for (int b = 0; b < 16; ++b) {
                int hb = hist[b];
                if (cum + hb >= need) { bsel = b; cntb = hb; break; }
                cum += hb;
            }
            if (cum + cntb == need) {   // boundary bin fully included: done
                bound = (unsigned long long)pref
                      + ((unsigned long long)(bsel + 1) << shift);
                break;
            }
            pref |= (unsigned int)bsel << shift;
            prefmask |= 0xFu << shift;
            need -= cum;
            // distinct keys guarantee termination by shift==0
        }
        // write pass: ballot-compacted, exactly KNN keys < bound
        unsigned int wbase = 0u;
        for (int a0 = 0; a0 < C; a0 += LPQ) {
            int a = a0 + l;
            bool selp = (a < C) && ((unsigned long long)cd[a] < bound);
            unsigned int sub = gballot(selp, grp);
            if (selp) {
                unsigned int k = cd[a];
                unsigned int off = __popc(sub & ((1u << l) - 1u));
                sel[wbase + off] = k;
                kmx = kmx > k ? kmx : k;
            }
            wbase += (unsigned int)__popc(sub);
        }
    }
    kmx = max(kmx, (unsigned int)__shfl_xor((int)kmx, 1));
    kmx = max(kmx, (unsigned int)__shfl_xor((int)kmx, 2));
    kmx = max(kmx, (unsigned int)__shfl_xor((int)kmx, 4));
    kmx = max(kmx, (unsigned int)__shfl_xor((int)kmx, 8));
    kmx = max(kmx, (unsigned int)__shfl_xor((int)kmx, 16));
    return kmx;
}

// Barrier-free grid kernel: 8 queries/block, 32 lanes/query (half wave).
__global__ __launch_bounds__(NTH2)
void rimls_grid(const float* __restrict__ qpts,
                const float* __restrict__ sverts,
                const float* __restrict__ snorms,
                const float4* __restrict__ spts,
                const unsigned int* __restrict__ cellend,
                const unsigned short* __restrict__ coarse16,
                const float* __restrict__ gp,
                float* __restrict__ out,
                int N)
{
    __shared__ unsigned int cand[QT2*CAPS2];            // 10272 B
    __shared__ unsigned int selk[QT2*KNN];              // 960 B
    __shared__ __align__(16) unsigned short ccnt[NCC];  // 8192 B
    __shared__ unsigned int cntq[QT2];                  // 32 B

    const int t = threadIdx.x;
    const int q = t >> 5;       // 0..7
    const int l = t & 31;       // lane within query group
    const int grp = q & 1;      // which half of the wave64

    if (t < QT2) cntq[t] = 0u;
    for (int i = t; i < QT2*KNN; i += NTH2) selk[i] = 0u;
    // coalesced copy of precomputed coarse counts: 512 uint4 total, 2 per thread
    {
        uint4* d = (uint4*)ccnt;
        const uint4* s = (const uint4*)coarse16;
        d[t] = s[t];
        d[t + 256] = s[t + 256];
    }
    __syncthreads();
    // ---- no block barriers beyond this point ----

    const float gx0 = gp[0], gy0 = gp[1], gz0 = gp[2];
    const float csx = gp[3], csy = gp[4], csz = gp[5];
    const float icx = gp[6], icy = gp[7], icz = gp[8];
    const float icsmin = gp[9], vcell = gp[10];
    const float ccsx = 4.0f*csx, ccsy = 4.0f*csy, ccsz = 4.0f*csz;

    int gq0 = blockIdx.x * QT2 + q; if (gq0 >= N) gq0 = N - 1;
    const float qx = qpts[3*gq0+0], qy = qpts[3*gq0+1], qz = qpts[3*gq0+2];
    int qcx = (int)floorf((qx - gx0) * icx); qcx = qcx < 0 ? 0 : (qcx >= RG ? RG-1 : qcx);
    int qcy = (int)floorf((qy - gy0) * icy); qcy = qcy < 0 ? 0 : (qcy >= RG ? RG-1 : qcy);
    int qcz = (int)floorf((qz - gz0) * icz); qcz = qcz < 0 ? 0 : (qcz >= RG ? RG-1 : qcz);
    const int qccx = qcx >> 2, qccy = qcy >> 2, qccz = qcz >> 2;

    // ---- phase A: grow coarse box (LDS counts, division-free walk) ----
    int S0 = 0; unsigned int cbox = 1u;
    int lxS = 0, hxS = 0, lyS = 0, hyS = 0, lzS = 0, hzS = 0;
    for (int s = 0; s < RC; ++s) {
        int lx = qccx - s; if (lx < 0) lx = 0;
        int hx = qccx + s; if (hx > RC-1) hx = RC-1;
        int ly = qccy - s; if (ly < 0) ly = 0;
        int hy = qccy + s; if (hy > RC-1) hy = RC-1;
        int lz = qccz - s; if (lz < 0) lz = 0;
        int hz = qccz + s; if (hz > RC-1) hz = RC-1;
        int bnx = hx-lx+1, bny = hy-ly+1, bnz = hz-lz+1;
        int tot = bnx*bny*bnz;
        unsigned int csum = 0u;
        int ix = l, iy = 0, iz = 0;
        while (ix >= bnx) { ix -= bnx; ++iy; }
        while (iy >= bny) { iy -= bny; ++iz; }
        for (int i = l; i < tot; i += LPQ) {
            csum += (unsigned int)ccnt[((lz+iz)*RC + (ly+iy))*RC + (lx+ix)];
            ix += LPQ;
            while (ix >= bnx) { ix -= bnx; ++iy; }
            while (iy >= bny) { iy -= bny; ++iz; }
        }
        csum += __shfl_xor(csum, 1);
        csum += __shfl_xor(csum, 2);
        csum += __shfl_xor(csum, 4);
        csum += __shfl_xor(csum, 8);
        csum += __shfl_xor(csum, 16);
        if (csum >= (unsigned)KNN || s == RC-1) {
            S0 = s; cbox = csum ? csum : 1u;
            lxS = lx; hxS = hx; lyS = ly; hyS = hy; lzS = lz; hzS = hz;
            break;
        }
    }

    // common: rigorous cap tc (corner of clipped S0 box)
    float tc;
    {
        float blx = gx0 + (float)lxS * ccsx, bhx = gx0 + (float)(hxS+1) * ccsx;
        float bly = gy0 + (float)lyS * ccsy, bhy = gy0 + (float)(hyS+1) * ccsy;
        float blz = gz0 + (float)lzS * ccsz, bhz = gz0 + (float)(hzS+1) * ccsz;
        float dfx = fmaxf(qx - blx, bhx - qx);
        float dfy = fmaxf(qy - bly, bhy - qy);
        float dfz = fmaxf(qz - blz, bhz - qz);
        tc = sqrtf(dfx*dfx + dfy*dfy + dfz*dfz) * 1.0001f + 1e-6f;
    }

    unsigned int* candp = cand + q*CAPS2;
    bool done_sel = false;   // selk already holds final neighbors
    bool ret = true;
    float T = tc, tlo = 0.0f, thi = 0.0f;
    float vol = (float)((hxS-lxS+1)*(hyS-lyS+1)*(hzS-lzS+1)) * vcell * 64.0f;
    float t0 = cbrtf(TGT * vol / (4.18879f * (float)cbox));

    if (cbox <= (unsigned)CAP2) {
        // ======== BOX PATH (tail/mid): cell-serial range-parallel collect ====
        // ======== + exact top-30 via radix select ============================
        unsigned int base = 0u;
        for (int iz = lzS; iz <= hzS; ++iz)
        for (int iy = lyS; iy <= hyS; ++iy)
        for (int ix = lxS; ix <= hxS; ++ix) {
            int cidx = (iz*RC + iy)*RC + ix;
            if (!ccnt[cidx]) continue;
            int cbase = cidx << 6;
            unsigned int b_ = cbase ? cellend[cbase-1] : 0u;
            unsigned int e_ = cellend[cbase+63];
            for (unsigned int p = b_ + (unsigned int)l; ; p += LPQ) {
                bool act = p < e_;
                unsigned int sub = gballot(act, grp);
                if (!sub) break;
                if (act) {
                    float4 sp = spts[p];
                    float ex = qx - sp.x, ey = qy - sp.y, ez = qz - sp.z;
                    float d2 = fmaf(ex, ex, fmaf(ey, ey, ez*ez));
                    unsigned int off = __popc(sub & ((1u << l) - 1u));
                    candp[base + off] = (__float_as_uint(d2) & 0xFFFF0000u)
                                      | (__float_as_uint(sp.w) & 0xFFFFu);
                }
                base += (unsigned int)__popc(sub);
            }
        }
        int C = (int)base;          // == cbox, in [KNN, CAP2]
        unsigned int kmx = radix_select(candp, C, selk + q*KNN, l, grp);
        float T2b = __uint_as_float(((kmx >> 16) + 1u) << 16);  // all 30 have d2 < T2b
        // inscribed radius^2 of box around q (clipped faces -> +inf: no points beyond bbox)
        float rins2;
        {
            float rxl = (lxS > 0)    ? (qx - (gx0 + (float)lxS * ccsx))     : 1e30f;
            float rxh = (hxS < RC-1) ? ((gx0 + (float)(hxS+1) * ccsx) - qx) : 1e30f;
            float ryl = (lyS > 0)    ? (qy - (gy0 + (float)lyS * ccsy))     : 1e30f;
            float ryh = (hyS < RC-1) ? ((gy0 + (float)(hyS+1) * ccsy) - qy) : 1e30f;
            float rzl = (lzS > 0)    ? (qz - (gz0 + (float)lzS * ccsz))     : 1e30f;
            float rzh = (hzS < RC-1) ? ((gz0 + (float)(hzS+1) * ccsz) - qz) : 1e30f;
            float rins = fminf(fminf(fminf(rxl, rxh), fminf(ryl, ryh)), fminf(rzl, rzh));
            rins = fmaxf(rins, 0.0f);
            rins2 = rins * rins;
        }
        if (T2b <= rins2) {
            done_sel = true; ret = false;   // ball(d30) inside box: selk is final
        } else {
            T = fminf(sqrtf(T2b), tc);      // one sweep; count >= KNN guaranteed
        }
    } else {
        // ======== DENSE PATH: density estimate + bracket bisection ========
        float tlo0 = 0.0f;
        if (S0 > 0) {
            float s1 = (float)(S0 - 1);
            float rx = fminf(qx - (gx0 + ((float)qccx - s1) * ccsx),
                             (gx0 + ((float)qccx + s1 + 1.0f) * ccsx) - qx);
            float ry = fminf(qy - (gy0 + ((float)qccy - s1) * ccsy),
                             (gy0 + ((float)qccy + s1 + 1.0f) * ccsy) - qy);
            float rz = fminf(qz - (gz0 + ((float)qccz - s1) * ccsz),
                             (gz0 + ((float)qccz + s1 + 1.0f) * ccsz) - qz);
            float rins = fminf(rx, fminf(ry, rz));
            tlo0 = fmaxf(rins, 0.0f) * 0.9999f;
        }
        tlo = tlo0;
        T = fminf(fmaxf(t0, tlo0 * 1.02f), tc);
    }

    // ---- phase B: probe + bracket bisection, per-group, barrier-free ----
    volatile unsigned int* cvp = &cntq[q];
    for (int round = 0; round < MAXR; ++round) {
        if (!__any(ret)) break;
        if (ret) {
            cntq[q] = 0u;
            float T2 = T*T;
            int smaxF = (int)(T * icsmin) + 1; if (smaxF > RG) smaxF = RG;
            if (smaxF <= 4) {
                // fine centered walk, cube side B <= 9, division-free
                int B = 2*smaxF + 1;
                int tot = B*B*B;
                int bx0 = qcx - smaxF, by0 = qcy - smaxF, bz0 = qcz - smaxF;
                int ix = l, iy = 0, iz = 0;
                while (ix >= B) { ix -= B; ++iy; }
                while (iy >= B) { iy -= B; ++iz; }
                for (int i = l; i < tot; i += LPQ) {
                    if (*cvp > (unsigned)CAP2) break;
                    int cx = bx0 + ix, cy = by0 + iy, cz = bz0 + iz;
                    if ((unsigned)cx < (unsigned)RG && (unsigned)cy < (unsigned)RG && (unsigned)cz < (unsigned)RG) {
                        float lox = gx0 + (float)cx * csx;
                        float loy = gy0 + (float)cy * csy;
                        float loz = gz0 + (float)cz * csz;
                        float ax_ = fmaxf(0.0f, fmaxf(lox - qx, qx - lox - csx));
                        float ay_ = fmaxf(0.0f, fmaxf(loy - qy, qy - loy - csy));
                        float az_ = fmaxf(0.0f, fmaxf(loz - qz, qz - loz - csz));
                        float md2 = fmaf(ax_, ax_, fmaf(ay_, ay_, az_*az_));
                        if (md2 < T2) {
                            int c = fidx(cx, cy, cz);
                            unsigned int b_ = c ? cellend[c-1] : 0u;
                            scan_range(spts, b_, cellend[c], qx, qy, qz, T2, &cntq[q], candp);
                        }
                    }
                    ix += LPQ;
                    while (ix >= B) { ix -= B; ++iy; }
                    while (iy >= B) { iy -= B; ++iz; }
                }
            } else {
                // coarse-skip walk; contiguous range scan per coarse cell when cheap
                int fx0 = qcx - smaxF, fx1 = qcx + smaxF;
                int fy0 = qcy - smaxF, fy1 = qcy + smaxF;
                int fz0 = qcz - smaxF, fz1 = qcz + smaxF;
                int cx0 = (fx0 < 0 ? 0 : fx0) >> 2, cx1 = (fx1 > RG-1 ? RG-1 : fx1) >> 2;
                int cy0 = (fy0 < 0 ? 0 : fy0) >> 2, cy1 = (fy1 > RG-1 ? RG-1 : fy1) >> 2;
                int cz0 = (fz0 < 0 ? 0 : fz0) >> 2, cz1 = (fz1 > RG-1 ? RG-1 : fz1) >> 2;
                int cnx = cx1-cx0+1, cny = cy1-cy0+1, cnz = cz1-cz0+1;
                int tot = cnx*cny*cnz;
                int ix = l, iy = 0, iz = 0;
                while (ix >= cnx) { ix -= cnx; ++iy; }
                while (iy >= cny) { iy -= cny; ++iz; }
                for (int i = l; i < tot; i += LPQ) {
                    if (*cvp > (unsigned)CAP2) break;
                    int ccx = cx0+ix, ccy = cy0+iy, ccz = cz0+iz;
                    ix += LPQ;
                    while (ix >= cnx) { ix -= cnx; ++iy; }
                    while (iy >= cny) { iy -= cny; ++iz; }
                    int cidx = (ccz*RC + ccy)*RC + ccx;
                    unsigned int pc = ccnt[cidx];
                    if (!pc) continue;
                    float clx = gx0 + (float)ccx * ccsx;
                    float cly = gy0 + (float)ccy * ccsy;
                    float clz = gz0 + (float)ccz * ccsz;
                    float bx_ = fmaxf(0.0f, fmaxf(clx - qx, qx - clx - ccsx));
                    float by_ = fmaxf(0.0f, fmaxf(cly - qy, qy - cly - ccsy));
                    float bz_ = fmaxf(0.0f, fmaxf(clz - qz, qz - clz - ccsz));
                    float cmd2 = fmaf(bx_, bx_, fmaf(by_, by_, bz_*bz_));
                    if (cmd2 >= T2) continue;
                    int cbase = cidx << 6;
                    unsigned int cb_ = cbase ? cellend[cbase-1] : 0u;
                    unsigned int ce_ = cellend[cbase+63];
                    float mxx = fmaxf(qx - clx, clx + ccsx - qx);
                    float mxy = fmaxf(qy - cly, cly + ccsy - qy);
                    float mxz = fmaxf(qz - clz, clz + ccsz - qz);
                    float cmx2 = mxx*mxx + mxy*mxy + mxz*mxz;
                    if (cmx2 < T2 || pc <= 96u) {
                        scan_range(spts, cb_, ce_, qx, qy, qz, T2, &cntq[q], candp);
                    } else {
                        float axv[4], ayv[4], azv[4];
                        #pragma unroll
                        for (int u2 = 0; u2 < 4; ++u2) {
                            float lox = clx + (float)u2 * csx;
                            axv[u2] = fmaxf(0.0f, fmaxf(lox - qx, qx - lox - csx));
                            float loy = cly + (float)u2 * csy;
                            ayv[u2] = fmaxf(0.0f, fmaxf(loy - qy, qy - loy - csy));
                            float loz = clz + (float)u2 * csz;
                            azv[u2] = fmaxf(0.0f, fmaxf(loz - qz, qz - loz - csz));
                        }
                        #pragma unroll
                        for (int fz = 0; fz < 4; ++fz) {
                            float pz2 = azv[fz]*azv[fz];
                            #pragma unroll
                            for (int fy = 0; fy < 4; ++fy) {
                                float pyz = fmaf(ayv[fy], ayv[fy], pz2);
                                if (pyz >= T2) continue;
                                #pragma unroll
                                for (int fx = 0; fx < 4; ++fx) {
                                    float md2 = fmaf(axv[fx], axv[fx], pyz);
                                    if (md2 < T2) {
                                        int c = cbase + ((fz<<4) | (fy<<2) | fx);
                                        unsigned int b_ = c ? cellend[c-1] : 0u;
                                        scan_range(spts, b_, cellend[c], qx, qy, qz, T2, &cntq[q], candp);
                                    }
                                }
                            }
                        }
                    }
                }
            }
            // controller (identical on all lanes of the group)
            unsigned int c_ = cntq[q];
            if (c_ >= (unsigned)KNN && c_ <= (unsigned)CAP2) {
                ret = false;
            } else if (round < MAXR-1) {
                float nT;
                if (c_ < (unsigned)KNN) {
                    tlo = T;
                    nT = (thi > 0.0f) ? sqrtf(tlo * thi)
                       : fminf(T * fminf(fmaxf(cbrtf(TGT / (float)(c_ ? c_ : 1u)), 1.25f), 2.5f), tc);
                } else {
                    thi = T;
                    nT = (tlo > 0.0f) ? sqrtf(tlo * thi)
                       : T * fminf(fmaxf(cbrtf(TGT / (float)c_), 0.30f), 0.75f);
                }
                T = fminf(nT, tc);
            } else {
                ret = false;    // exhausted; belt in phase D handles gracefully
            }
        }
    }

    // ---- phase C: exact selection (skipped if box path finished) ----
    if (!done_sel) {
        unsigned int cc = cntq[q];
        int C = (int)(cc < (unsigned)CAP2 ? cc : (unsigned)CAP2);
        radix_select(candp, C, selk + q*KNN, l, grp);
    }

    // ---- phase D: epilogue (one neighbor per lane) ----
    {
        unsigned int ccq = cntq[q];
        int Cq = done_sel ? KNN : (int)(ccq < (unsigned)CAP2 ? ccq : (unsigned)CAP2);
        int kmax = Cq < KNN ? Cq : KNN;

        bool v = (l < kmax);
        int j = v ? (int)(selk[q*KNN + l] & 0xFFFFu) : 0;
        float sx = sverts[3*j+0], sy = sverts[3*j+1], sz = sverts[3*j+2];
        float px = qx - sx, py = qy - sy, pz = qz - sz;
        float r2 = px*px + py*py + pz*pz;
        float nx = snorms[3*j+0], ny = snorms[3*j+1], nz = snorms[3*j+2];
        float nrm = sqrtf(nx*nx + ny*ny + nz*nz);
        float inv = 1.0f / fmaxf(nrm, 1e-8f);
        float m0 = v ? 1.0f : 0.0f;
        nx *= inv * m0; ny *= inv * m0; nz *= inv * m0;
        px *= m0; py *= m0; pz *= m0;
        float r2m = r2 * m0;
        float fxv = px*nx + py*ny + pz*nz;
        float dsum = v ? sqrtf(r2) : 0.0f;
        dsum += __shfl_xor(dsum, 1);
        dsum += __shfl_xor(dsum, 2);
        dsum += __shfl_xor(dsum, 4);
        dsum += __shfl_xor(dsum, 8);
        dsum += __shfl_xor(dsum, 16);
        float h = dsum * (1.0f / (float)KNN) + 1e-8f;
        float h2 = h * h;
        float c8 = -8.0f / h2;
        float tt = fmaxf(1.0f - r2m / h2, 0.0f);
        float t2 = tt * tt;
        float phi = t2 * t2 * m0;
        float gco = c8 * t2 * tt * m0;

        const float inv_sn2 = 1.0f / (SIGMA_N * SIGMA_N);
        float f = 0.0f, gx = 0.0f, gy = 0.0f, gz = 0.0f;
        bool done = false;
        for (int it = 0; it < 3; ++it) {
            if (done) break;
            float alpha = 1.0f;
            if (it > 0) {
                float dx = nx-gx, dy = ny-gy, dz = nz-gz;
                alpha = expf(-(dx*dx + dy*dy + dz*dz) * inv_sn2);
            }
            float w = alpha * phi;
            float g = alpha * gco;
            float gf = g * fxv;
            float sw  = w,      swf = w * fxv;
            float sgx = g*px,   sgy = g*py,   sgz = g*pz;
            float sfx = gf*px,  sfy = gf*py,  sfz = gf*pz;
            float snx = w*nx,   sny = w*ny,   snz = w*nz;
            #pragma unroll
            for (int m = 1; m < LPQ; m <<= 1) {
                sw  += __shfl_xor(sw, m);  swf += __shfl_xor(swf, m);
                sgx += __shfl_xor(sgx, m); sgy += __shfl_xor(sgy, m); sgz += __shfl_xor(sgz, m);
                sfx += __shfl_xor(sfx, m); sfy += __shfl_xor(sfy, m); sfz += __shfl_xor(sfz, m);
                snx += __shfl_xor(snx, m); sny += __shfl_xor(sny, m); snz += __shfl_xor(snz, m);
            }
            sw += 1e-8f;
            float fn  = swf / sw;
            float gnx = (sfx + snx - fn*sgx) / sw;
            float gny = (sfy + sny - fn*sgy) / sw;
            float gnz = (sfz + snz - fn*sgz) / sw;
            float delta = fabsf(fn - f);
            f = fn; gx = gnx; gy = gny; gz = gnz;
            done = (delta < THRESHV);
        }
        if (l == 0) {
            if (gq0 < N) {
                out[gq0] = f;
                out[N + 3*gq0 + 0] = gx;
                out[N + 3*gq0 + 1] = gy;
                out[N + 3*gq0 + 2] = gz;
            }
        }
    }
}

// ============================================================

extern "C" void kernel_launch(void* const* d_in, const int* in_sizes, int n_in,
                              void* d_out, int out_size, void* d_ws, size_t ws_size,
                              hipStream_t stream) {
    (void)n_in; (void)out_size;
    const float* qpts   = (const float*)d_in[0];
    const float* sverts = (const float*)d_in[1];
    const float* snorms = (const float*)d_in[2];
    float* out = (float*)d_out;
    int N = in_sizes[0] / 3;
    int M = in_sizes[1] / 3;

    size_t need_grid = (size_t)M * 16 + (size_t)NC * 4 + 256 * 4 + 12 * 4 + (size_t)NCC * 2;

    if (ws_size >= need_grid && M <= 65536) {
        char* w = (char*)d_ws;
        float4*         spts = (float4*)w;
        unsigned int*   offs = (unsigned int*)(w + (size_t)M * 16);
        unsigned int*   aux  = offs + NC;
        float*          gp   = (float*)(aux + 256);
        unsigned short* c16  = (unsigned short*)(gp + 12);

        int mb = (M + 255) / 256;
        hipMemsetAsync(offs, 0, (size_t)NC * 4, stream);
        grid_bboxparams<<<1, 1024, 0, stream>>>(sverts, gp, M);
        grid_count  <<<mb, 256, 0, stream>>>(sverts, gp, offs, M);
        grid_scan_tile<<<NC / 1024, 256, 0, stream>>>(offs, aux);
        grid_scan_aux <<<1, 256, 0, stream>>>(aux);
        grid_scan_add <<<NC / 1024, 256, 0, stream>>>(offs, aux);
        grid_scatter<<<mb, 256, 0, stream>>>(sverts, gp, offs, spts, M);
        grid_coarse16<<<(NCC + 255) / 256, 256, 0, stream>>>(offs, c16);

        int blocks = (N + QT2 - 1) / QT2;
        rimls_grid<<<blocks, NTH2, 0, stream>>>(qpts, sverts, snorms, spts, offs, c16, gp, out, N);
    } else {
        int blocks = (N + QT - 1) / QT;
        if (ws_size >= (size_t)M * sizeof(float4)) {
            float4* spack = (float4*)d_ws;
            prep_pack<<<(M + 255) / 256, 256, 0, stream>>>(sverts, spack, M);
            rimls_fused<true><<<blocks, NTH, 0, stream>>>(qpts, sverts, snorms, spack, out, N, M);
        } else {
            rimls_fused<false><<<blocks, NTH, 0, stream>>>(qpts, sverts, snorms, nullptr, out, N, M);
        }
    }
}

// Round 15
// 374.542 us; speedup vs baseline: 1.1032x; 1.1032x over previous
//
#include <hip/hip_runtime.h>
#include <math.h>

#define KNN 30
#define SIGMA_N 0.8f
#define THRESHV 1e-3f

// ---------------- old (fallback) path constants ----------------
#define QT 32
#define NTH 256
#define CAP 160
#define CAPS 161
#define RSEL 20

// ---------------- grid path constants ----------------
#define RG 64
#define NC (RG*RG*RG)
#define RC 16                    // coarse grid (RG/4)
#define NCC (RC*RC*RC)
#define QT2 8                    // queries per block
#define NTH2 256
#define LPQ 32                   // lanes per query (half wave)
#define CAP2 320
#define CAPS2 321
#define TGT 60.0f
#define MAXR 12

// ============================================================
// ===============  OLD BRUTE-FORCE PATH (fallback) ===========
// ============================================================

__global__ void prep_pack(const float* __restrict__ src, float4* __restrict__ dst, int M) {
    int j = blockIdx.x * 256 + threadIdx.x;
    if (j < M) {
        float x = src[3*j+0], y = src[3*j+1], z = src[3*j+2];
        dst[j] = make_float4(x, y, z, 0.5f*(x*x + y*y + z*z));
    }
}

template<bool PACKED>
__device__ __forceinline__ float4 fetch_pt(const float4* __restrict__ sp,
                                           const float* __restrict__ sv, int j) {
    if (PACKED) return sp[j];
    float x = sv[3*j+0], y = sv[3*j+1], z = sv[3*j+2];
    return make_float4(x, y, z, 0.5f*(x*x + y*y + z*z));
}

__device__ __forceinline__ void ins4(unsigned int k, unsigned int &m0, unsigned int &m1,
                                     unsigned int &m2, unsigned int &m3) {
    if (k < m3) {
        if (k < m2) {
            m3 = m2;
            if (k < m1) { m2 = m1; if (k < m0) { m1 = m0; m0 = k; } else m1 = k; }
            else m2 = k;
        } else m3 = k;
    }
}

template<bool PACKED>
__global__ __launch_bounds__(NTH)
void rimls_fused(const float* __restrict__ qpts,
                 const float* __restrict__ sverts,
                 const float* __restrict__ snorms,
                 const float4* __restrict__ spack,
                 float* __restrict__ out,
                 int N, int M)
{
    __shared__ unsigned int cand[QT * CAPS];
    __shared__ unsigned int selk[QT * KNN];
    __shared__ float4 qbuf[QT];
    __shared__ unsigned int cnt[QT];
    __shared__ unsigned int T16[QT];
    __shared__ int retryq[QT];

    const int t  = threadIdx.x;
    const int qg = t >> 4;
    const int c  = t & 15;
    const int qa = qg, qb = qg + 16;

    if (t < QT) {
        int gq = blockIdx.x * QT + t; if (gq >= N) gq = N - 1;
        float x = qpts[3*gq+0], y = qpts[3*gq+1], z = qpts[3*gq+2];
        qbuf[t] = make_float4(x, y, z, 0.5f*(x*x + y*y + z*z));
    }
    for (int i = t; i < QT * KNN; i += NTH) selk[i] = 0u;
    __syncthreads();

    const float ax = qbuf[qa].x, ay = qbuf[qa].y, az = qbuf[qa].z, aw = qbuf[qa].w;
    const float bx = qbuf[qb].x, by = qbuf[qb].y, bz = qbuf[qb].z, bw = qbuf[qb].w;

    unsigned int a0=~0u,a1=~0u,a2=~0u,a3=~0u, b0=~0u,b1=~0u,b2=~0u,b3=~0u;
    {
        const int n1 = M >> 6;
        #pragma unroll 2
        for (int i = 0; i < n1; ++i) {
            int j = (c + (i << 4)) << 2;
            float4 s = fetch_pt<PACKED>(spack, sverts, j);
            float va = fmaxf(fmaf(-ax, s.x, fmaf(-ay, s.y, fmaf(-az, s.z, s.w + aw))), 0.0f);
            float vb = fmaxf(fmaf(-bx, s.x, fmaf(-by, s.y, fmaf(-bz, s.z, s.w + bw))), 0.0f);
            unsigned int ka = (__float_as_uint(va) & 0xFFFF0000u) | (unsigned int)j;
            unsigned int kb = (__float_as_uint(vb) & 0xFFFF0000u) | (unsigned int)j;
            ins4(ka, a0, a1, a2, a3);
            ins4(kb, b0, b1, b2, b3);
        }
    }
    {
        unsigned int* mb = cand;
        mb[qa*64 + c*4 + 0] = a0; mb[qa*64 + c*4 + 1] = a1;
        mb[qa*64 + c*4 + 2] = a2; mb[qa*64 + c*4 + 3] = a3;
        mb[qb*64 + c*4 + 0] = b0; mb[qb*64 + c*4 + 1] = b1;
        mb[qb*64 + c*4 + 2] = b2; mb[qb*64 + c*4 + 3] = b3;
    }
    __syncthreads();
    if (t < QT) {
        const unsigned int* m_ = cand + t * 64;
        unsigned int kth = 0xFFFFFFFFu;
        for (int a = 0; a < 64; ++a) {
            unsigned int ka = m_[a]; int r = 0;
            for (int b = 0; b < 64; ++b) r += (m_[b] < ka) ? 1 : 0;
            if (r == RSEL - 1) kth = ka;
        }
        unsigned int tb = (kth >> 16) + 1u;
        if (tb > 0x7F00u) tb = 0x7F00u;
        T16[t] = tb; cnt[t] = 0u; retryq[t] = 1;
    }
    __syncthreads();

    const int n3 = M >> 4;
    for (int round = 0; round < 8; ++round) {
        bool aa = retryq[qa] != 0, ab = retryq[qb] != 0;
        if (aa || ab) {
            float Ta = aa ? __uint_as_float(T16[qa] << 16) : 0.0f;
            float Tb = ab ? __uint_as_float(T16[qb] << 16) : 0.0f;
            #pragma unroll 4
            for (int i = 0; i < n3; ++i) {
                int j = c + (i << 4);
                float4 s = fetch_pt<PACKED>(spack, sverts, j);
                float va = fmaxf(fmaf(-ax, s.x, fmaf(-ay, s.y, fmaf(-az, s.z, s.w + aw))), 0.0f);
                float vb = fmaxf(fmaf(-bx, s.x, fmaf(-by, s.y, fmaf(-bz, s.z, s.w + bw))), 0.0f);
                if (va < Ta) {
                    unsigned int pos = atomicAdd(&cnt[qa], 1u);
                    if (pos < (unsigned)CAP)
                        cand[qa*CAPS + pos] = (__float_as_uint(va) & 0xFFFF0000u) | (unsigned int)j;
                }
                if (vb < Tb) {
                    unsigned int pos = atomicAdd(&cnt[qb], 1u);
                    if (pos < (unsigned)CAP)
                        cand[qb*CAPS + pos] = (__float_as_uint(vb) & 0xFFFF0000u) | (unsigned int)j;
                }
            }
        }
        __syncthreads();
        int bad = 0;
        if (t < QT && retryq[t]) {
            unsigned int cc = cnt[t], tb = T16[t];
            if (cc < (unsigned)KNN) {
                if (tb < 0x7F00u) {
                    tb += (1u << 7);
                    if (tb > 0x7F00u) tb = 0x7F00u;
                    bad = 1;
                }
            } else if (cc > (unsigned)CAP && round < 4 && tb > (1u << 6)) {
                tb -= (1u << 6); bad = 1;
            }
            if (bad) { T16[t] = tb; cnt[t] = 0u; }
            else retryq[t] = 0;
        }
        if (!__syncthreads_or(bad)) break;
    }

    const int qs = t >> 3, s8 = t & 7;
    {
        unsigned int cc = cnt[qs];
        int C = (int)(cc < (unsigned)CAP ? cc : (unsigned)CAP);
        const unsigned int* cd = cand + qs * CAPS;
        for (int a = s8; a < C; a += 8) {
            unsigned int ka = cd[a]; int r = 0;
            for (int b = 0; b < C; ++b) r += (cd[b] < ka) ? 1 : 0;
            if (r < KNN) selk[qs*KNN + r] = ka;
        }
    }
    __syncthreads();

    {
        const float qx = qbuf[qs].x, qy = qbuf[qs].y, qz = qbuf[qs].z;
        float px_[4], py_[4], pz_[4], nx_[4], ny_[4], nz_[4];
        float fx_[4], phi_[4], gco_[4], r2_[4];
        float dsum = 0.0f;
        #pragma unroll
        for (int u = 0; u < 4; ++u) {
            int k = s8 + 8*u;
            bool v = (k < KNN);
            int j = v ? (int)(selk[qs*KNN + k] & 0xFFFFu) : 0;
            float4 s = fetch_pt<PACKED>(spack, sverts, j);
            float px = qx - s.x, py = qy - s.y, pz = qz - s.z;
            float r2 = px*px + py*py + pz*pz;
            float nx = snorms[3*j+0], ny = snorms[3*j+1], nz = snorms[3*j+2];
            float nrm = sqrtf(nx*nx + ny*ny + nz*nz);
            float inv = 1.0f / fmaxf(nrm, 1e-8f);
            float m = v ? 1.0f : 0.0f;
            nx *= inv * m; ny *= inv * m; nz *= inv * m;
            px_[u] = px * m; py_[u] = py * m; pz_[u] = pz * m;
            nx_[u] = nx; ny_[u] = ny; nz_[u] = nz;
            r2_[u] = r2 * m;
            fx_[u] = px_[u]*nx + py_[u]*ny + pz_[u]*nz;
            dsum += v ? sqrtf(r2) : 0.0f;
            phi_[u] = m;
        }
        dsum += __shfl_xor(dsum, 1);
        dsum += __shfl_xor(dsum, 2);
        dsum += __shfl_xor(dsum, 4);
        float h = dsum * (1.0f / (float)KNN) + 1e-8f;
        float h2 = h * h;
        float c8 = -8.0f / h2;
        #pragma unroll
        for (int u = 0; u < 4; ++u) {
            float tt = fmaxf(1.0f - r2_[u] / h2, 0.0f);
            float t2 = tt * tt;
            float valid = phi_[u];
            phi_[u] = t2 * t2 * valid;
            gco_[u] = c8 * t2 * tt * valid;
        }

        const float inv_sn2 = 1.0f / (SIGMA_N * SIGMA_N);
        float f = 0.0f, gx = 0.0f, gy = 0.0f, gz = 0.0f;
        bool done = false;
        for (int it = 0; it < 3; ++it) {
            if (done) break;
            float sw=0, swf=0, sgx=0, sgy=0, sgz=0, sfx=0, sfy=0, sfz=0, snx=0, sny=0, snz=0;
            #pragma unroll
            for (int u = 0; u < 4; ++u) {
                float alpha = 1.0f;
                if (it > 0) {
                    float dx = nx_[u]-gx, dy = ny_[u]-gy, dz = nz_[u]-gz;
                    alpha = expf(-(dx*dx + dy*dy + dz*dz) * inv_sn2);
                }
                float w = alpha * phi_[u];
                float g = alpha * gco_[u];
                float gf = g * fx_[u];
                sw  += w;          swf += w * fx_[u];
                sgx += g*px_[u];   sgy += g*py_[u];   sgz += g*pz_[u];
                sfx += gf*px_[u];  sfy += gf*py_[u];  sfz += gf*pz_[u];
                snx += w*nx_[u];   sny += w*ny_[u];   snz += w*nz_[u];
            }
            #pragma unroll
            for (int m = 1; m < 8; m <<= 1) {
                sw  += __shfl_xor(sw, m);  swf += __shfl_xor(swf, m);
                sgx += __shfl_xor(sgx, m); sgy += __shfl_xor(sgy, m); sgz += __shfl_xor(sgz, m);
                sfx += __shfl_xor(sfx, m); sfy += __shfl_xor(sfy, m); sfz += __shfl_xor(sfz, m);
                snx += __shfl_xor(snx, m); sny += __shfl_xor(sny, m); snz += __shfl_xor(snz, m);
            }
            sw += 1e-8f;
            float fn  = swf / sw;
            float gnx = (sfx + snx - fn*sgx) / sw;
            float gny = (sfy + sny - fn*sgy) / sw;
            float gnz = (sfz + snz - fn*sgz) / sw;
            float delta = fabsf(fn - f);
            f = fn; gx = gnx; gy = gny; gz = gnz;
            done = (delta < THRESHV);
        }
        if (s8 == 0) {
            int gq = blockIdx.x * QT + qs;
            if (gq < N) {
                out[gq] = f;
                out[N + 3*gq + 0] = gx;
                out[N + 3*gq + 1] = gy;
                out[N + 3*gq + 2] = gz;
            }
        }
    }
}

// ============================================================
// ===============  GRID KNN PATH  ============================
// ============================================================

__device__ __forceinline__ unsigned int enc_f(float f) {
    unsigned int b = __float_as_uint(f);
    return (b & 0x80000000u) ? ~b : (b | 0x80000000u);
}
__device__ __forceinline__ float dec_f(unsigned int u) {
    unsigned int b = (u & 0x80000000u) ? (u ^ 0x80000000u) : ~u;
    return __uint_as_float(b);
}
__device__ __forceinline__ int cell_of(float v, float mn, float ics) {
    int c = (int)floorf((v - mn) * ics);
    return c < 0 ? 0 : (c >= RG ? RG-1 : c);
}
// coarse-major fine-cell index: each coarse cell's 64 fine cells (and thus its
// points after scatter) are CONTIGUOUS
__device__ __forceinline__ int fidx(int cx, int cy, int cz) {
    int cidx = (((cz >> 2)*RC + (cy >> 2))*RC + (cx >> 2));
    return (cidx << 6) | ((cz & 3) << 4) | ((cy & 3) << 2) | (cx & 3);
}

// fused bbox + grid params: single block, 1024 threads
__global__ void grid_bboxparams(const float* __restrict__ sv, float* __restrict__ gp, int M) {
    __shared__ unsigned int rmn[3][16], rmx[3][16];
    const int t = threadIdx.x;
    unsigned int mn0=0xFFFFFFFFu, mn1=0xFFFFFFFFu, mn2=0xFFFFFFFFu;
    unsigned int mx0=0u, mx1=0u, mx2=0u;
    for (int i = t; i < M; i += 1024) {
        unsigned int e0 = enc_f(sv[3*i+0]);
        unsigned int e1 = enc_f(sv[3*i+1]);
        unsigned int e2 = enc_f(sv[3*i+2]);
        mn0 = min(mn0, e0); mn1 = min(mn1, e1); mn2 = min(mn2, e2);
        mx0 = max(mx0, e0); mx1 = max(mx1, e1); mx2 = max(mx2, e2);
    }
    for (int off = 1; off < 64; off <<= 1) {
        mn0 = min(mn0, (unsigned int)__shfl_xor(mn0, off));
        mn1 = min(mn1, (unsigned int)__shfl_xor(mn1, off));
        mn2 = min(mn2, (unsigned int)__shfl_xor(mn2, off));
        mx0 = max(mx0, (unsigned int)__shfl_xor(mx0, off));
        mx1 = max(mx1, (unsigned int)__shfl_xor(mx1, off));
        mx2 = max(mx2, (unsigned int)__shfl_xor(mx2, off));
    }
    if ((t & 63) == 0) {
        int w = t >> 6;
        rmn[0][w]=mn0; rmn[1][w]=mn1; rmn[2][w]=mn2;
        rmx[0][w]=mx0; rmx[1][w]=mx1; rmx[2][w]=mx2;
    }
    __syncthreads();
    if (t == 0) {
        for (int w = 1; w < 16; ++w) {
            rmn[0][0]=min(rmn[0][0],rmn[0][w]); rmn[1][0]=min(rmn[1][0],rmn[1][w]); rmn[2][0]=min(rmn[2][0],rmn[2][w]);
            rmx[0][0]=max(rmx[0][0],rmx[0][w]); rmx[1][0]=max(rmx[1][0],rmx[1][w]); rmx[2][0]=max(rmx[2][0],rmx[2][w]);
        }
        float csmin = 1e30f, vcell = 1.0f;
        for (int a = 0; a < 3; ++a) {
            float mn = dec_f(rmn[a][0]), mx = dec_f(rmx[a][0]);
            float span = mx - mn;
            if (!(span > 1e-5f)) span = 1e-5f;
            float cs = span / (float)RG;
            gp[a] = mn; gp[3+a] = cs; gp[6+a] = 1.0f / cs;
            csmin = fminf(csmin, cs); vcell *= cs;
        }
        gp[9]  = 1.0f / csmin;
        gp[10] = vcell;
    }
}

__global__ void grid_count(const float* __restrict__ sv, const float* __restrict__ gp,
                           unsigned int* __restrict__ offs, int M) {
    int i = blockIdx.x * 256 + threadIdx.x;
    if (i >= M) return;
    int cx = cell_of(sv[3*i+0], gp[0], gp[6]);
    int cy = cell_of(sv[3*i+1], gp[1], gp[7]);
    int cz = cell_of(sv[3*i+2], gp[2], gp[8]);
    atomicAdd(&offs[fidx(cx, cy, cz)], 1u);
}

__global__ void grid_scan_tile(unsigned int* __restrict__ offs, unsigned int* __restrict__ aux) {
    __shared__ unsigned int sm[256];
    const int tid = threadIdx.x;
    const int base = blockIdx.x * 1024 + tid * 4;
    uint4 v = *(const uint4*)&offs[base];
    v.y += v.x; v.z += v.y; v.w += v.z;
    sm[tid] = v.w;
    __syncthreads();
    for (int off = 1; off < 256; off <<= 1) {
        unsigned int add = (tid >= off) ? sm[tid - off] : 0u;
        __syncthreads();
        sm[tid] += add;
        __syncthreads();
    }
    unsigned int add = tid ? sm[tid-1] : 0u;
    v.x += add; v.y += add; v.z += add; v.w += add;
    *(uint4*)&offs[base] = v;
    if (tid == 255) aux[blockIdx.x] = sm[255];
}

__global__ void grid_scan_aux(unsigned int* __restrict__ aux) {
    __shared__ unsigned int sm[256];
    const int tid = threadIdx.x;
    sm[tid] = aux[tid];
    __syncthreads();
    for (int off = 1; off < 256; off <<= 1) {
        unsigned int add = (tid >= off) ? sm[tid - off] : 0u;
        __syncthreads();
        sm[tid] += add;
        __syncthreads();
    }
    aux[tid] = tid ? sm[tid-1] : 0u;
}

__global__ void grid_scan_add(unsigned int* __restrict__ offs, const unsigned int* __restrict__ aux) {
    __shared__ unsigned int sm[1024];
    const int tid = threadIdx.x;
    const int base = blockIdx.x * 1024;
    uint4 v = *(const uint4*)&offs[base + tid*4];
    sm[tid*4+0] = v.x; sm[tid*4+1] = v.y; sm[tid*4+2] = v.z; sm[tid*4+3] = v.w;
    __syncthreads();
    unsigned int a = aux[blockIdx.x];
    uint4 o;
    o.x = a + (tid ? sm[tid*4-1] : 0u);
    o.y = a + sm[tid*4+0];
    o.z = a + sm[tid*4+1];
    o.w = a + sm[tid*4+2];
    *(uint4*)&offs[base + tid*4] = o;
}

__global__ void grid_scatter(const float* __restrict__ sv, const float* __restrict__ gp,
                             unsigned int* __restrict__ offs, float4* __restrict__ spts, int M) {
    int i = blockIdx.x * 256 + threadIdx.x;
    if (i >= M) return;
    float x = sv[3*i+0], y = sv[3*i+1], z = sv[3*i+2];
    int cx = cell_of(x, gp[0], gp[6]);
    int cy = cell_of(y, gp[1], gp[7]);
    int cz = cell_of(z, gp[2], gp[8]);
    unsigned int pos = atomicAdd(&offs[fidx(cx, cy, cz)], 1u);
    spts[pos] = make_float4(x, y, z, __uint_as_float((unsigned int)i));
}

// derive u16 coarse counts once (post-scatter cellend)
__global__ void grid_coarse16(const unsigned int* __restrict__ cellend,
                              unsigned short* __restrict__ c16) {
    int i = blockIdx.x * 256 + threadIdx.x;
    if (i >= NCC) return;
    unsigned int e_ = cellend[(i << 6) + 63];
    unsigned int b_ = i ? cellend[(i << 6) - 1] : 0u;
    unsigned int v = e_ - b_;
    c16[i] = (unsigned short)(v > 65535u ? 65535u : v);
}

// scan a contiguous point range with threshold filter; aborts on overshoot
__device__ __forceinline__ void scan_range(const float4* __restrict__ spts,
                                           unsigned int b_, unsigned int e_,
                                           float qx, float qy, float qz, float T2,
                                           unsigned int* cntp, unsigned int* candp) {
    for (unsigned int p = b_; p < e_; ++p) {
        if (((p - b_) & 15u) == 0u &&
            *(volatile unsigned int*)cntp > (unsigned)CAP2) return;
        float4 sp = spts[p];
        float ex = qx - sp.x, ey = qy - sp.y, ez = qz - sp.z;
        float d2 = fmaf(ex, ex, fmaf(ey, ey, ez*ez));
        if (d2 < T2) {
            unsigned int pos = atomicAdd(cntp, 1u);
            if (pos < (unsigned)CAP2)
                candp[pos] = (__float_as_uint(d2) & 0xFFFF0000u) | (__float_as_uint(sp.w) & 0xFFFFu);
        }
    }
}

// Exact selection of the KNN smallest among C DISTINCT keys (distinctness:
// low 16 bits are the unique point index). Writes the selected set to
// sel[0..min(C,KNN)) in ARBITRARY order (consumer is order-independent),
// returns the max selected key (the exact "30th-smallest"). 4-bit MSD radix
// with early termination; typically 2-3 counting passes + 1 write pass.
// hist: 16-entry LDS region private to this query group.
__device__ __forceinline__ unsigned int radix_select(
        const unsigned int* __restrict__ cd, int C,
        unsigned int* __restrict__ sel, int l, int grp,
        volatile unsigned int* hist)
{
    unsigned int kmx = 0u;
    if (C <= KNN) {
        for (int a = l; a < C; a += LPQ) {
            unsigned int k = cd[a];
            sel[a] = k;
            kmx = kmx > k ? kmx : k;
        }
    } else {
        unsigned int pref = 0u, prefmask = 0u;
        int need = KNN;
        unsigned long long bound = 0ull;
        for (int shift = 28; shift >= 0; shift -= 4) {
            if (l < 16) hist[l] = 0u;
            for (int a = l; a < C; a += LPQ) {
                unsigned int k = cd[a];
                if ((k & prefmask) == pref)
                    atomicAdd((unsigned int*)&hist[(k >> shift) & 15u], 1u);
            }
            int cum = 0, bsel = 0, cntb = 0;
            #pragma unroll 1
            for (int b = 0; b < 16; ++b) {
                int hb = (int)hist[b];
                if (cum + hb >= need) { bsel = b; cntb = hb; break; }
                cum += hb;
            }
            if (cum + cntb == need) {   // boundary bin fully included: done
                bound = (unsigned long long)pref
                      + ((unsigned long long)(bsel + 1) << shift);
                break;
            }
            pref |= (unsigned int)bsel << shift;
            prefmask |= 0xFu << shift;
            need -= cum;
            // distinct keys guarantee termination by shift==0
        }
        // write pass: ballot-compacted, exactly KNN keys < bound
        unsigned int wbase = 0u;
        for (int a0 = 0; a0 < C; a0 += LPQ) {
            int a = a0 + l;
            bool selp = (a < C) && ((unsigned long long)cd[a] < bound);
            unsigned long long mb = __ballot(selp);
            unsigned int sub = (unsigned int)(mb >> (grp << 5));
            if (selp) {
                unsigned int k = cd[a];
                unsigned int off = __popc(sub & ((1u << l) - 1u));
                sel[wbase + off] = k;
                kmx = kmx > k ? kmx : k;
            }
            wbase += (unsigned int)__popc(sub);
        }
    }
    kmx = max(kmx, (unsigned int)__shfl_xor((int)kmx, 1));
    kmx = max(kmx, (unsigned int)__shfl_xor((int)kmx, 2));
    kmx = max(kmx, (unsigned int)__shfl_xor((int)kmx, 4));
    kmx = max(kmx, (unsigned int)__shfl_xor((int)kmx, 8));
    kmx = max(kmx, (unsigned int)__shfl_xor((int)kmx, 16));
    return kmx;
}

// Barrier-free grid kernel: 8 queries/block, 32 lanes/query (half wave).
__global__ __launch_bounds__(NTH2)
void rimls_grid(const float* __restrict__ qpts,
                const float* __restrict__ sverts,
                const float* __restrict__ snorms,
                const float4* __restrict__ spts,
                const unsigned int* __restrict__ cellend,
                const unsigned short* __restrict__ coarse16,
                const float* __restrict__ gp,
                float* __restrict__ out,
                int N)
{
    __shared__ unsigned int cand[QT2*CAPS2];            // 10272 B
    __shared__ unsigned int selk[QT2*KNN];              // 960 B
    __shared__ __align__(16) unsigned short ccnt[NCC];  // 8192 B
    __shared__ unsigned int cntq[QT2];                  // 32 B
    __shared__ unsigned int hist[QT2*16];               // 512 B (radix bins)

    const int t = threadIdx.x;
    const int q = t >> 5;       // 0..7
    const int l = t & 31;       // lane within query group
    const int grp = q & 1;      // which half of the wave64

    if (t < QT2) cntq[t] = 0u;
    for (int i = t; i < QT2*KNN; i += NTH2) selk[i] = 0u;
    // coalesced copy of precomputed coarse counts: 512 uint4 total, 2 per thread
    {
        uint4* d = (uint4*)ccnt;
        const uint4* s = (const uint4*)coarse16;
        d[t] = s[t];
        d[t + 256] = s[t + 256];
    }
    __syncthreads();
    // ---- no block barriers beyond this point ----

    const float gx0 = gp[0], gy0 = gp[1], gz0 = gp[2];
    const float csx = gp[3], csy = gp[4], csz = gp[5];
    const float icx = gp[6], icy = gp[7], icz = gp[8];
    const float icsmin = gp[9], vcell = gp[10];
    const float ccsx = 4.0f*csx, ccsy = 4.0f*csy, ccsz = 4.0f*csz;

    int gq0 = blockIdx.x * QT2 + q; if (gq0 >= N) gq0 = N - 1;
    const float qx = qpts[3*gq0+0], qy = qpts[3*gq0+1], qz = qpts[3*gq0+2];
    int qcx = (int)floorf((qx - gx0) * icx); qcx = qcx < 0 ? 0 : (qcx >= RG ? RG-1 : qcx);
    int qcy = (int)floorf((qy - gy0) * icy); qcy = qcy < 0 ? 0 : (qcy >= RG ? RG-1 : qcy);
    int qcz = (int)floorf((qz - gz0) * icz); qcz = qcz < 0 ? 0 : (qcz >= RG ? RG-1 : qcz);
    const int qccx = qcx >> 2, qccy = qcy >> 2, qccz = qcz >> 2;

    // ---- phase A: grow coarse box (LDS counts, division-free walk) ----
    int S0 = 0; unsigned int cbox = 1u;
    int lxS = 0, hxS = 0, lyS = 0, hyS = 0, lzS = 0, hzS = 0;
    for (int s = 0; s < RC; ++s) {
        int lx = qccx - s; if (lx < 0) lx = 0;
        int hx = qccx + s; if (hx > RC-1) hx = RC-1;
        int ly = qccy - s; if (ly < 0) ly = 0;
        int hy = qccy + s; if (hy > RC-1) hy = RC-1;
        int lz = qccz - s; if (lz < 0) lz = 0;
        int hz = qccz + s; if (hz > RC-1) hz = RC-1;
        int bnx = hx-lx+1, bny = hy-ly+1, bnz = hz-lz+1;
        int tot = bnx*bny*bnz;
        unsigned int csum = 0u;
        int ix = l, iy = 0, iz = 0;
        while (ix >= bnx) { ix -= bnx; ++iy; }
        while (iy >= bny) { iy -= bny; ++iz; }
        for (int i = l; i < tot; i += LPQ) {
            csum += (unsigned int)ccnt[((lz+iz)*RC + (ly+iy))*RC + (lx+ix)];
            ix += LPQ;
            while (ix >= bnx) { ix -= bnx; ++iy; }
            while (iy >= bny) { iy -= bny; ++iz; }
        }
        csum += __shfl_xor(csum, 1);
        csum += __shfl_xor(csum, 2);
        csum += __shfl_xor(csum, 4);
        csum += __shfl_xor(csum, 8);
        csum += __shfl_xor(csum, 16);
        if (csum >= (unsigned)KNN || s == RC-1) {
            S0 = s; cbox = csum ? csum : 1u;
            lxS = lx; hxS = hx; lyS = ly; hyS = hy; lzS = lz; hzS = hz;
            break;
        }
    }

    // common: rigorous cap tc (corner of clipped S0 box)
    float tc;
    {
        float blx = gx0 + (float)lxS * ccsx, bhx = gx0 + (float)(hxS+1) * ccsx;
        float bly = gy0 + (float)lyS * ccsy, bhy = gy0 + (float)(hyS+1) * ccsy;
        float blz = gz0 + (float)lzS * ccsz, bhz = gz0 + (float)(hzS+1) * ccsz;
        float dfx = fmaxf(qx - blx, bhx - qx);
        float dfy = fmaxf(qy - bly, bhy - qy);
        float dfz = fmaxf(qz - blz, bhz - qz);
        tc = sqrtf(dfx*dfx + dfy*dfy + dfz*dfz) * 1.0001f + 1e-6f;
    }

    unsigned int* candp = cand + q*CAPS2;
    volatile unsigned int* histp = (volatile unsigned int*)(hist + q*16);
    bool done_sel = false;   // selk already holds final neighbors
    bool ret = true;
    float T = tc, tlo = 0.0f, thi = 0.0f;
    float vol = (float)((hxS-lxS+1)*(hyS-lyS+1)*(hzS-lzS+1)) * vcell * 64.0f;
    float t0 = cbrtf(TGT * vol / (4.18879f * (float)cbox));

    if (cbox <= (unsigned)CAP2) {
        // ======== BOX PATH (tail/mid): cell-serial range-parallel collect ====
        // ======== + exact top-30 via radix select ============================
        unsigned int base = 0u;
        for (int iz = lzS; iz <= hzS; ++iz)
        for (int iy = lyS; iy <= hyS; ++iy)
        for (int ix = lxS; ix <= hxS; ++ix) {
            int cidx = (iz*RC + iy)*RC + ix;
            if (!ccnt[cidx]) continue;
            int cbase = cidx << 6;
            unsigned int b_ = cbase ? cellend[cbase-1] : 0u;
            unsigned int e_ = cellend[cbase+63];
            for (unsigned int p = b_ + (unsigned int)l; ; p += LPQ) {
                bool act = p < e_;
                unsigned long long mb = __ballot(act);
                unsigned int sub = (unsigned int)(mb >> (grp << 5));
                if (!sub) break;
                if (act) {
                    float4 sp = spts[p];
                    float ex = qx - sp.x, ey = qy - sp.y, ez = qz - sp.z;
                    float d2 = fmaf(ex, ex, fmaf(ey, ey, ez*ez));
                    unsigned int off = __popc(sub & ((1u << l) - 1u));
                    candp[base + off] = (__float_as_uint(d2) & 0xFFFF0000u)
                                      | (__float_as_uint(sp.w) & 0xFFFFu);
                }
                base += (unsigned int)__popc(sub);
            }
        }
        int C = (int)base;          // == cbox, in [KNN, CAP2]
        unsigned int kmx = radix_select(candp, C, selk + q*KNN, l, grp, histp);
        float T2b = __uint_as_float(((kmx >> 16) + 1u) << 16);  // all 30 have d2 < T2b
        // inscribed radius^2 of box around q (clipped faces -> +inf: no points beyond bbox)
        float rins2;
        {
            float rxl = (lxS > 0)    ? (qx - (gx0 + (float)lxS * ccsx))     : 1e30f;
            float rxh = (hxS < RC-1) ? ((gx0 + (float)(hxS+1) * ccsx) - qx) : 1e30f;
            float ryl = (lyS > 0)    ? (qy - (gy0 + (float)lyS * ccsy))     : 1e30f;
            float ryh = (hyS < RC-1) ? ((gy0 + (float)(hyS+1) * ccsy) - qy) : 1e30f;
            float rzl = (lzS > 0)    ? (qz - (gz0 + (float)lzS * ccsz))     : 1e30f;
            float rzh = (hzS < RC-1) ? ((gz0 + (float)(hzS+1) * ccsz) - qz) : 1e30f;
            float rins = fminf(fminf(fminf(rxl, rxh), fminf(ryl, ryh)), fminf(rzl, rzh));
            rins = fmaxf(rins, 0.0f);
            rins2 = rins * rins;
        }
        if (T2b <= rins2) {
            done_sel = true; ret = false;   // ball(d30) inside box: selk is final
        } else {
            T = fminf(sqrtf(T2b), tc);      // one sweep; count >= KNN guaranteed
        }
    } else {
        // ======== DENSE PATH: density estimate + bracket bisection ========
        float tlo0 = 0.0f;
        if (S0 > 0) {
            float s1 = (float)(S0 - 1);
            float rx = fminf(qx - (gx0 + ((float)qccx - s1) * ccsx),
                             (gx0 + ((float)qccx + s1 + 1.0f) * ccsx) - qx);
            float ry = fminf(qy - (gy0 + ((float)qccy - s1) * ccsy),
                             (gy0 + ((float)qccy + s1 + 1.0f) * ccsy) - qy);
            float rz = fminf(qz - (gz0 + ((float)qccz - s1) * ccsz),
                             (gz0 + ((float)qccz + s1 + 1.0f) * ccsz) - qz);
            float rins = fminf(rx, fminf(ry, rz));
            tlo0 = fmaxf(rins, 0.0f) * 0.9999f;
        }
        tlo = tlo0;
        T = fminf(fmaxf(t0, tlo0 * 1.02f), tc);
    }

    // ---- phase B: probe + bracket bisection, per-group, barrier-free ----
    volatile unsigned int* cvp = &cntq[q];
    for (int round = 0; round < MAXR; ++round) {
        if (!__any(ret)) break;
        if (ret) {
            cntq[q] = 0u;
            float T2 = T*T;
            int smaxF = (int)(T * icsmin) + 1; if (smaxF > RG) smaxF = RG;
            if (smaxF <= 4) {
                // fine centered walk, cube side B <= 9, division-free
                int B = 2*smaxF + 1;
                int tot = B*B*B;
                int bx0 = qcx - smaxF, by0 = qcy - smaxF, bz0 = qcz - smaxF;
                int ix = l, iy = 0, iz = 0;
                while (ix >= B) { ix -= B; ++iy; }
                while (iy >= B) { iy -= B; ++iz; }
                for (int i = l; i < tot; i += LPQ) {
                    if (*cvp > (unsigned)CAP2) break;
                    int cx = bx0 + ix, cy = by0 + iy, cz = bz0 + iz;
                    if ((unsigned)cx < (unsigned)RG && (unsigned)cy < (unsigned)RG && (unsigned)cz < (unsigned)RG) {
                        float lox = gx0 + (float)cx * csx;
                        float loy = gy0 + (float)cy * csy;
                        float loz = gz0 + (float)cz * csz;
                        float ax_ = fmaxf(0.0f, fmaxf(lox - qx, qx - lox - csx));
                        float ay_ = fmaxf(0.0f, fmaxf(loy - qy, qy - loy - csy));
                        float az_ = fmaxf(0.0f, fmaxf(loz - qz, qz - loz - csz));
                        float md2 = fmaf(ax_, ax_, fmaf(ay_, ay_, az_*az_));
                        if (md2 < T2) {
                            int c = fidx(cx, cy, cz);
                            unsigned int b_ = c ? cellend[c-1] : 0u;
                            scan_range(spts, b_, cellend[c], qx, qy, qz, T2, &cntq[q], candp);
                        }
                    }
                    ix += LPQ;
                    while (ix >= B) { ix -= B; ++iy; }
                    while (iy >= B) { iy -= B; ++iz; }
                }
            } else {
                // coarse-skip walk; contiguous range scan per coarse cell when cheap
                int fx0 = qcx - smaxF, fx1 = qcx + smaxF;
                int fy0 = qcy - smaxF, fy1 = qcy + smaxF;
                int fz0 = qcz - smaxF, fz1 = qcz + smaxF;
                int cx0 = (fx0 < 0 ? 0 : fx0) >> 2, cx1 = (fx1 > RG-1 ? RG-1 : fx1) >> 2;
                int cy0 = (fy0 < 0 ? 0 : fy0) >> 2, cy1 = (fy1 > RG-1 ? RG-1 : fy1) >> 2;
                int cz0 = (fz0 < 0 ? 0 : fz0) >> 2, cz1 = (fz1 > RG-1 ? RG-1 : fz1) >> 2;
                int cnx = cx1-cx0+1, cny = cy1-cy0+1, cnz = cz1-cz0+1;
                int tot = cnx*cny*cnz;
                int ix = l, iy = 0, iz = 0;
                while (ix >= cnx) { ix -= cnx; ++iy; }
                while (iy >= cny) { iy -= cny; ++iz; }
                for (int i = l; i < tot; i += LPQ) {
                    if (*cvp > (unsigned)CAP2) break;
                    int ccx = cx0+ix, ccy = cy0+iy, ccz = cz0+iz;
                    ix += LPQ;
                    while (ix >= cnx) { ix -= cnx; ++iy; }
                    while (iy >= cny) { iy -= cny; ++iz; }
                    int cidx = (ccz*RC + ccy)*RC + ccx;
                    unsigned int pc = ccnt[cidx];
                    if (!pc) continue;
                    float clx = gx0 + (float)ccx * ccsx;
                    float cly = gy0 + (float)ccy * ccsy;
                    float clz = gz0 + (float)ccz * ccsz;
                    float bx_ = fmaxf(0.0f, fmaxf(clx - qx, qx - clx - ccsx));
                    float by_ = fmaxf(0.0f, fmaxf(cly - qy, qy - cly - ccsy));
                    float bz_ = fmaxf(0.0f, fmaxf(clz - qz, qz - clz - ccsz));
                    float cmd2 = fmaf(bx_, bx_, fmaf(by_, by_, bz_*bz_));
                    if (cmd2 >= T2) continue;
                    int cbase = cidx << 6;
                    unsigned int cb_ = cbase ? cellend[cbase-1] : 0u;
                    unsigned int ce_ = cellend[cbase+63];
                    float mxx = fmaxf(qx - clx, clx + ccsx - qx);
                    float mxy = fmaxf(qy - cly, cly + ccsy - qy);
                    float mxz = fmaxf(qz - clz, clz + ccsz - qz);
                    float cmx2 = mxx*mxx + mxy*mxy + mxz*mxz;
                    if (cmx2 < T2 || pc <= 96u) {
                        scan_range(spts, cb_, ce_, qx, qy, qz, T2, &cntq[q], candp);
                    } else {
                        float axv[4], ayv[4], azv[4];
                        #pragma unroll
                        for (int u2 = 0; u2 < 4; ++u2) {
                            float lox = clx + (float)u2 * csx;
                            axv[u2] = fmaxf(0.0f, fmaxf(lox - qx, qx - lox - csx));
                            float loy = cly + (float)u2 * csy;
                            ayv[u2] = fmaxf(0.0f, fmaxf(loy - qy, qy - loy - csy));
                            float loz = clz + (float)u2 * csz;
                            azv[u2] = fmaxf(0.0f, fmaxf(loz - qz, qz - loz - csz));
                        }
                        #pragma unroll
                        for (int fz = 0; fz < 4; ++fz) {
                            float pz2 = azv[fz]*azv[fz];
                            #pragma unroll
                            for (int fy = 0; fy < 4; ++fy) {
                                float pyz = fmaf(ayv[fy], ayv[fy], pz2);
                                if (pyz >= T2) continue;
                                #pragma unroll
                                for (int fx = 0; fx < 4; ++fx) {
                                    float md2 = fmaf(axv[fx], axv[fx], pyz);
                                    if (md2 < T2) {
                                        int c = cbase + ((fz<<4) | (fy<<2) | fx);
                                        unsigned int b_ = c ? cellend[c-1] : 0u;
                                        scan_range(spts, b_, cellend[c], qx, qy, qz, T2, &cntq[q], candp);
                                    }
                                }
                            }
                        }
                    }
                }
            }
            // controller (identical on all lanes of the group)
            unsigned int c_ = cntq[q];
            if (c_ >= (unsigned)KNN && c_ <= (unsigned)CAP2) {
                ret = false;
            } else if (round < MAXR-1) {
                float nT;
                if (c_ < (unsigned)KNN) {
                    tlo = T;
                    nT = (thi > 0.0f) ? sqrtf(tlo * thi)
                       : fminf(T * fminf(fmaxf(cbrtf(TGT / (float)(c_ ? c_ : 1u)), 1.25f), 2.5f), tc);
                } else {
                    thi = T;
                    nT = (tlo > 0.0f) ? sqrtf(tlo * thi)
                       : T * fminf(fmaxf(cbrtf(TGT / (float)c_), 0.30f), 0.75f);
                }
                T = fminf(nT, tc);
            } else {
                ret = false;    // exhausted; belt in phase D handles gracefully
            }
        }
    }

    // ---- phase C: exact selection (skipped if box path finished) ----
    if (!done_sel) {
        unsigned int cc = cntq[q];
        int C = (int)(cc < (unsigned)CAP2 ? cc : (unsigned)CAP2);
        radix_select(candp, C, selk + q*KNN, l, grp, histp);
    }

    // ---- phase D: epilogue (one neighbor per lane) ----
    {
        unsigned int ccq = cntq[q];
        int Cq = done_sel ? KNN : (int)(ccq < (unsigned)CAP2 ? ccq : (unsigned)CAP2);
        int kmax = Cq < KNN ? Cq : KNN;

        bool v = (l < kmax);
        int j = v ? (int)(selk[q*KNN + l] & 0xFFFFu) : 0;
        float sx = sverts[3*j+0], sy = sverts[3*j+1], sz = sverts[3*j+2];
        float px = qx - sx, py = qy - sy, pz = qz - sz;
        float r2 = px*px + py*py + pz*pz;
        float nx = snorms[3*j+0], ny = snorms[3*j+1], nz = snorms[3*j+2];
        float nrm = sqrtf(nx*nx + ny*ny + nz*nz);
        float inv = 1.0f / fmaxf(nrm, 1e-8f);
        float m0 = v ? 1.0f : 0.0f;
        nx *= inv * m0; ny *= inv * m0; nz *= inv * m0;
        px *= m0; py *= m0; pz *= m0;
        float r2m = r2 * m0;
        float fxv = px*nx + py*ny + pz*nz;
        float dsum = v ? sqrtf(r2) : 0.0f;
        dsum += __shfl_xor(dsum, 1);
        dsum += __shfl_xor(dsum, 2);
        dsum += __shfl_xor(dsum, 4);
        dsum += __shfl_xor(dsum, 8);
        dsum += __shfl_xor(dsum, 16);
        float h = dsum * (1.0f / (float)KNN) + 1e-8f;
        float h2 = h * h;
        float c8 = -8.0f / h2;
        float tt = fmaxf(1.0f - r2m / h2, 0.0f);
        float t2 = tt * tt;
        float phi = t2 * t2 * m0;
        float gco = c8 * t2 * tt * m0;

        const float inv_sn2 = 1.0f / (SIGMA_N * SIGMA_N);
        float f = 0.0f, gx = 0.0f, gy = 0.0f, gz = 0.0f;
        bool done = false;
        for (int it = 0; it < 3; ++it) {
            if (done) break;
            float alpha = 1.0f;
            if (it > 0) {
                float dx = nx-gx, dy = ny-gy, dz = nz-gz;
                alpha = expf(-(dx*dx + dy*dy + dz*dz) * inv_sn2);
            }
            float w = alpha * phi;
            float g = alpha * gco;
            float gf = g * fxv;
            float sw  = w,      swf = w * fxv;
            float sgx = g*px,   sgy = g*py,   sgz = g*pz;
            float sfx = gf*px,  sfy = gf*py,  sfz = gf*pz;
            float snx = w*nx,   sny = w*ny,   snz = w*nz;
            #pragma unroll
            for (int m = 1; m < LPQ; m <<= 1) {
                sw  += __shfl_xor(sw, m);  swf += __shfl_xor(swf, m);
                sgx += __shfl_xor(sgx, m); sgy += __shfl_xor(sgy, m); sgz += __shfl_xor(sgz, m);
                sfx += __shfl_xor(sfx, m); sfy += __shfl_xor(sfy, m); sfz += __shfl_xor(sfz, m);
                snx += __shfl_xor(snx, m); sny += __shfl_xor(sny, m); snz += __shfl_xor(snz, m);
            }
            sw += 1e-8f;
            float fn  = swf / sw;
            float gnx = (sfx + snx - fn*sgx) / sw;
            float gny = (sfy + sny - fn*sgy) / sw;
            float gnz = (sfz + snz - fn*sgz) / sw;
            float delta = fabsf(fn - f);
            f = fn; gx = gnx; gy = gny; gz = gnz;
            done = (delta < THRESHV);
        }
        if (l == 0) {
            if (gq0 < N) {
                out[gq0] = f;
                out[N + 3*gq0 + 0] = gx;
                out[N + 3*gq0 + 1] = gy;
                out[N + 3*gq0 + 2] = gz;
            }
        }
    }
}

// ============================================================

extern "C" void kernel_launch(void* const* d_in, const int* in_sizes, int n_in,
                              void* d_out, int out_size, void* d_ws, size_t ws_size,
                              hipStream_t stream) {
    (void)n_in; (void)out_size;
    const float* qpts   = (const float*)d_in[0];
    const float* sverts = (const float*)d_in[1];
    const float* snorms = (const float*)d_in[2];
    float* out = (float*)d_out;
    int N = in_sizes[0] / 3;
    int M = in_sizes[1] / 3;

    size_t need_grid = (size_t)M * 16 + (size_t)NC * 4 + 256 * 4 + 12 * 4 + (size_t)NCC * 2;

    if (ws_size >= need_grid && M <= 65536) {
        char* w = (char*)d_ws;
        float4*         spts = (float4*)w;
        unsigned int*   offs = (unsigned int*)(w + (size_t)M * 16);
        unsigned int*   aux  = offs + NC;
        float*          gp   = (float*)(aux + 256);
        unsigned short* c16  = (unsigned short*)(gp + 12);

        int mb = (M + 255) / 256;
        hipMemsetAsync(offs, 0, (size_t)NC * 4, stream);
        grid_bboxparams<<<1, 1024, 0, stream>>>(sverts, gp, M);
        grid_count  <<<mb, 256, 0, stream>>>(sverts, gp, offs, M);
        grid_scan_tile<<<NC / 1024, 256, 0, stream>>>(offs, aux);
        grid_scan_aux <<<1, 256, 0, stream>>>(aux);
        grid_scan_add <<<NC / 1024, 256, 0, stream>>>(offs, aux);
        grid_scatter<<<mb, 256, 0, stream>>>(sverts, gp, offs, spts, M);
        grid_coarse16<<<(NCC + 255) / 256, 256, 0, stream>>>(offs, c16);

        int blocks = (N + QT2 - 1) / QT2;
        rimls_grid<<<blocks, NTH2, 0, stream>>>(qpts, sverts, snorms, spts, offs, c16, gp, out, N);
    } else {
        int blocks = (N + QT - 1) / QT;
        if (ws_size >= (size_t)M * sizeof(float4)) {
            float4* spack = (float4*)d_ws;
            prep_pack<<<(M + 255) / 256, 256, 0, stream>>>(sverts, spack, M);
            rimls_fused<true><<<blocks, NTH, 0, stream>>>(qpts, sverts, snorms, spack, out, N, M);
        } else {
            rimls_fused<false><<<blocks, NTH, 0, stream>>>(qpts, sverts, snorms, nullptr, out, N, M);
        }
    }
}